// Round 2
// baseline (490.477 us; speedup 1.0000x reference)
//
#include <hip/hip_runtime.h>
#include <hip/hip_bf16.h>

#define HEADS 4
#define C 32
#define OUTCH 128   // HEADS*C
#define INCH 128
#define NEG_SLOPE 0.2f

// ---------------------------------------------------------------------------
// CSR offsets (per-node degree + scan)
// ---------------------------------------------------------------------------
__global__ void k_count(const int* __restrict__ dst, int* __restrict__ deg, int E) {
    int e = blockIdx.x * 256 + threadIdx.x;
    if (e < E) atomicAdd(&deg[dst[e]], 1);
}

// per-block inclusive scan of 1024-element tiles
__global__ __launch_bounds__(1024) void k_scan1(const int* __restrict__ deg,
                                                int* __restrict__ incl,
                                                int* __restrict__ bsum, int n) {
    __shared__ int sm[1024];
    int t = threadIdx.x;
    int g = blockIdx.x * 1024 + t;
    int v = (g < n) ? deg[g] : 0;
    sm[t] = v;
    __syncthreads();
    for (int off = 1; off < 1024; off <<= 1) {
        int add = (t >= off) ? sm[t - off] : 0;
        __syncthreads();
        sm[t] += add;
        __syncthreads();
    }
    if (g < n) incl[g] = sm[t];
    if (t == 1023) bsum[blockIdx.x] = sm[t];
}

// exclusive scan of <=64 block sums (one wave)
__global__ void k_scan2(int* __restrict__ bsum, int nb) {
    int t = threadIdx.x;  // 64 threads
    int v = (t < nb) ? bsum[t] : 0;
    int orig = v;
    for (int off = 1; off < 64; off <<= 1) {
        int u = __shfl_up(v, off);
        if (t >= off) v += u;
    }
    if (t < nb) bsum[t] = v - orig;  // exclusive
}

__global__ __launch_bounds__(1024) void k_scan3(const int* __restrict__ incl,
                                                const int* __restrict__ bsumx,
                                                const int* __restrict__ deg,
                                                int* __restrict__ offs, int n) {
    int g = blockIdx.x * 1024 + threadIdx.x;
    if (g < n) offs[g] = incl[g] + bsumx[blockIdx.x] - deg[g];
}

// ---------------------------------------------------------------------------
// Bucketed edge scatter (XCD-local multisplit). bucket = dst >> 7 (128 nodes).
// ---------------------------------------------------------------------------
__global__ __launch_bounds__(256) void k_bhist(const int* __restrict__ dst,
                                               int* __restrict__ cnt, int E, int NB) {
    __shared__ int lh[512];
    int grp = blockIdx.x & 7;
    for (int i = threadIdx.x; i < NB; i += 256) lh[i] = 0;
    __syncthreads();
    for (int e = blockIdx.x * 256 + threadIdx.x; e < E; e += 256 * gridDim.x)
        atomicAdd(&lh[dst[e] >> 7], 1);
    __syncthreads();
    for (int b = threadIdx.x; b < NB; b += 256) {
        int c = lh[b];
        if (c) atomicAdd(&cnt[grp * NB + b], c);
    }
}

// single-block exclusive scan of cnt[total] -> sOff (+sentinel), copy to bcur
__global__ __launch_bounds__(1024) void k_scan_cnt(const int* __restrict__ cnt,
                                                   int* __restrict__ sOff,
                                                   int* __restrict__ bcur, int total) {
    __shared__ int sm[1024];
    int t = threadIdx.x;
    int v[4];
    int sum = 0;
#pragma unroll
    for (int j = 0; j < 4; ++j) {
        int i = t * 4 + j;
        v[j] = (i < total) ? cnt[i] : 0;
        sum += v[j];
    }
    sm[t] = sum;
    __syncthreads();
    for (int off = 1; off < 1024; off <<= 1) {
        int add = (t >= off) ? sm[t - off] : 0;
        __syncthreads();
        sm[t] += add;
        __syncthreads();
    }
    int excl = sm[t] - sum;
#pragma unroll
    for (int j = 0; j < 4; ++j) {
        int i = t * 4 + j;
        if (i < total) { sOff[i] = excl; bcur[i] = excl; }
        excl += v[j];
    }
    if (t == 1023) sOff[total] = excl;  // sentinel = E
}

// append packed (local_dst<<25 | src) into (grp,bucket) segment
__global__ __launch_bounds__(256) void k_bscatter(const int* __restrict__ src,
                                                  const int* __restrict__ dst,
                                                  int* __restrict__ bcur,
                                                  unsigned int* __restrict__ pairs,
                                                  int E, int NB) {
    int grp = blockIdx.x & 7;
    for (int e = blockIdx.x * 256 + threadIdx.x; e < E; e += 256 * gridDim.x) {
        int d = dst[e];
        int b = d >> 7;
        int pos = atomicAdd(&bcur[grp * NB + b], 1);
        pairs[pos] = ((unsigned)(d & 127) << 25) | (unsigned)src[e];
    }
}

// one block per bucket: fine scatter into the bucket's srcl window (L2-local)
__global__ __launch_bounds__(256) void k_bfill(const unsigned int* __restrict__ pairs,
                                               const int* __restrict__ sOff,
                                               const int* __restrict__ offs,
                                               int* __restrict__ srcl, int NB, int n) {
    __shared__ int cur[128];
    int b = blockIdx.x;
    int n0 = b << 7;
    int t = threadIdx.x;
    if (t < 128) {
        int node = n0 + t;
        cur[t] = (node < n) ? offs[node] : 0;
    }
    __syncthreads();
#pragma unroll
    for (int g = 0; g < 8; ++g) {
        int beg = sOff[g * NB + b];
        int end = sOff[g * NB + b + 1];
        for (int i = beg + t; i < end; i += 256) {
            unsigned p = pairs[i];
            int local = p >> 25;
            int s = p & 0x1FFFFFF;
            int pos = atomicAdd(&cur[local], 1);
            srcl[pos] = s;
        }
    }
}

// ---------------------------------------------------------------------------
// h = x @ W   (f32, 64-row tile per block, W streamed through L1/L2)
// ---------------------------------------------------------------------------
__global__ __launch_bounds__(256) void k_gemm(const float* __restrict__ x,
                                              const float* __restrict__ W,
                                              float* __restrict__ h, int n) {
    __shared__ float xs[64][128];
    int t = threadIdx.x;
    int rowBase = blockIdx.x * 64;
    for (int i = t; i < 64 * 32; i += 256) {
        int r = i >> 5, c4 = i & 31;
        float4 v = {0.f, 0.f, 0.f, 0.f};
        if (rowBase + r < n)
            v = *(const float4*)(x + (size_t)(rowBase + r) * INCH + c4 * 4);
        *(float4*)&xs[r][c4 * 4] = v;
    }
    __syncthreads();

    int colg = t & 31;
    int rowg = t >> 5;
    float acc[8][4] = {};
    const float4* W4 = (const float4*)W;
    for (int k = 0; k < 128; ++k) {
        float4 w = W4[k * 32 + colg];
#pragma unroll
        for (int i = 0; i < 8; ++i) {
            float xv = xs[rowg * 8 + i][k];
            acc[i][0] = fmaf(xv, w.x, acc[i][0]);
            acc[i][1] = fmaf(xv, w.y, acc[i][1]);
            acc[i][2] = fmaf(xv, w.z, acc[i][2]);
            acc[i][3] = fmaf(xv, w.w, acc[i][3]);
        }
    }
#pragma unroll
    for (int i = 0; i < 8; ++i) {
        int r = rowBase + rowg * 8 + i;
        if (r < n)
            *(float4*)(h + (size_t)r * OUTCH + colg * 4) = *(float4*)acc[i];
    }
}

// ---------------------------------------------------------------------------
// per-node attention logits
// ---------------------------------------------------------------------------
__global__ __launch_bounds__(256) void k_logits(const float* __restrict__ h,
                                                const float* __restrict__ att_src,
                                                const float* __restrict__ att_dst,
                                                float* __restrict__ a_src,
                                                float* __restrict__ a_dst, int n) {
    int t = blockIdx.x * 256 + threadIdx.x;
    int i = t >> 2, head = t & 3;
    if (i >= n) return;
    const float4* hv = (const float4*)(h + (size_t)i * OUTCH + head * C);
    const float4* as4 = (const float4*)(att_src + head * C);
    const float4* ad4 = (const float4*)(att_dst + head * C);
    float ssum = 0.f, dsum = 0.f;
#pragma unroll
    for (int j = 0; j < 8; ++j) {
        float4 v = hv[j], a = as4[j], b = ad4[j];
        ssum += v.x * a.x + v.y * a.y + v.z * a.z + v.w * a.w;
        dsum += v.x * b.x + v.y * b.y + v.z * b.z + v.w * b.w;
    }
    a_src[(size_t)i * 4 + head] = ssum;
    a_dst[(size_t)i * 4 + head] = dsum;
}

// ---------------------------------------------------------------------------
// aggregation: one wave per destination node.
// ---------------------------------------------------------------------------
__global__ __launch_bounds__(256) void k_aggr(const float* __restrict__ h,
                                              const float* __restrict__ a_src,
                                              const float* __restrict__ a_dst,
                                              const int* __restrict__ offs,
                                              const int* __restrict__ deg,
                                              const int* __restrict__ srcl,
                                              const float* __restrict__ bias,
                                              float* __restrict__ out, int n) {
    int w = (blockIdx.x * 256 + threadIdx.x) >> 6;
    if (w >= n) return;
    int lane = threadIdx.x & 63;
    int head = lane >> 4;
    int ch = lane << 1;

    float adst = a_dst[(size_t)w * 4 + head];
    float al = a_src[(size_t)w * 4 + head] + adst;
    al = al > 0.f ? al : NEG_SLOPE * al;
    float ex = __expf(al);
    float2 hv = *(const float2*)(h + (size_t)w * OUTCH + ch);
    float denom = ex;
    float acc0 = ex * hv.x, acc1 = ex * hv.y;

    int start = offs[w], d = deg[w];
    int e = 0;
    for (; e + 2 <= d; e += 2) {
        int s0 = srcl[start + e];
        int s1 = srcl[start + e + 1];
        float as0 = a_src[(size_t)s0 * 4 + head];
        float as1 = a_src[(size_t)s1 * 4 + head];
        float2 h0 = *(const float2*)(h + (size_t)s0 * OUTCH + ch);
        float2 h1 = *(const float2*)(h + (size_t)s1 * OUTCH + ch);
        float b0 = as0 + adst; b0 = b0 > 0.f ? b0 : NEG_SLOPE * b0;
        float b1 = as1 + adst; b1 = b1 > 0.f ? b1 : NEG_SLOPE * b1;
        float e0 = __expf(b0), e1 = __expf(b1);
        denom += e0 + e1;
        acc0 = fmaf(e0, h0.x, acc0); acc1 = fmaf(e0, h0.y, acc1);
        acc0 = fmaf(e1, h1.x, acc0); acc1 = fmaf(e1, h1.y, acc1);
    }
    if (e < d) {
        int s0 = srcl[start + e];
        float as0 = a_src[(size_t)s0 * 4 + head];
        float2 h0 = *(const float2*)(h + (size_t)s0 * OUTCH + ch);
        float b0 = as0 + adst; b0 = b0 > 0.f ? b0 : NEG_SLOPE * b0;
        float e0 = __expf(b0);
        denom += e0;
        acc0 = fmaf(e0, h0.x, acc0); acc1 = fmaf(e0, h0.y, acc1);
    }
    float inv = 1.0f / denom;
    out[(size_t)w * OUTCH + ch]     = acc0 * inv + bias[ch];
    out[(size_t)w * OUTCH + ch + 1] = acc1 * inv + bias[ch + 1];
}

// ---------------------------------------------------------------------------
extern "C" void kernel_launch(void* const* d_in, const int* in_sizes, int n_in,
                              void* d_out, int out_size, void* d_ws, size_t ws_size,
                              hipStream_t stream) {
    const float* x       = (const float*)d_in[0];
    const int*   edge    = (const int*)d_in[1];
    const float* W       = (const float*)d_in[2];
    const float* att_src = (const float*)d_in[3];
    const float* att_dst = (const float*)d_in[4];
    const float* bias    = (const float*)d_in[5];
    float* out = (float*)d_out;

    const int N = in_sizes[0] / INCH;
    const int E = in_sizes[1] / 2;
    const int* esrc = edge;
    const int* edst = edge + E;

    const int NB = (N + 127) >> 7;       // buckets of 128 dst nodes
    const int CNT_TOT = 8 * NB;

    auto align = [](size_t v) { return (v + 255) & ~(size_t)255; };
    char* p = (char*)d_ws;
    float* h      = (float*)p; p += align((size_t)N * OUTCH * 4);
    float* a_src  = (float*)p; p += align((size_t)N * 4 * 4);
    float* a_dst  = (float*)p; p += align((size_t)N * 4 * 4);
    int*   deg    = (int*)p;   p += align((size_t)N * 4);
    int*   incl   = (int*)p;   p += align((size_t)N * 4);
    int*   offs   = (int*)p;   p += align((size_t)N * 4);
    int*   bsum   = (int*)p;   p += align(64 * 4);
    int*   cnt    = (int*)p;   p += align((size_t)CNT_TOT * 4);
    int*   sOff   = (int*)p;   p += align((size_t)(CNT_TOT + 1) * 4);
    int*   bcur   = (int*)p;   p += align((size_t)CNT_TOT * 4);
    unsigned int* pairs = (unsigned int*)p; p += align((size_t)E * 4);
    int*   srcl   = (int*)p;   p += align((size_t)E * 4);

    const int SB = (N + 1023) / 1024;

    hipMemsetAsync(deg, 0, (size_t)N * 4, stream);
    hipMemsetAsync(cnt, 0, (size_t)CNT_TOT * 4, stream);

    k_count<<<(E + 255) / 256, 256, 0, stream>>>(edst, deg, E);
    k_scan1<<<SB, 1024, 0, stream>>>(deg, incl, bsum, N);
    k_scan2<<<1, 64, 0, stream>>>(bsum, SB);
    k_scan3<<<SB, 1024, 0, stream>>>(incl, bsum, deg, offs, N);

    k_bhist<<<256, 256, 0, stream>>>(edst, cnt, E, NB);
    k_scan_cnt<<<1, 1024, 0, stream>>>(cnt, sOff, bcur, CNT_TOT);
    k_bscatter<<<1024, 256, 0, stream>>>(esrc, edst, bcur, pairs, E, NB);
    k_bfill<<<NB, 256, 0, stream>>>(pairs, sOff, offs, srcl, NB, N);

    k_gemm<<<(N + 63) / 64, 256, 0, stream>>>(x, W, h, N);
    k_logits<<<(N * 4 + 255) / 256, 256, 0, stream>>>(h, att_src, att_dst, a_src, a_dst, N);
    k_aggr<<<(N + 3) / 4, 256, 0, stream>>>(h, a_src, a_dst, offs, deg, srcl, bias, out, N);
}